// Round 1
// baseline (187.952 us; speedup 1.0000x reference)
//
#include <hip/hip_runtime.h>

// Skeleton forward kinematics: angles [B,16,6] f32, xyz [1,16,3] f32 -> out [B,16,3] f32.
// One thread per batch element; tree walk with (Rw,pw) chain state + branch-save at joint 3.

namespace {

constexpr int NJ = 16;

__device__ __forceinline__ void rot6d(const float a[6], float R[9]) {
    // b1 = normalize(a[0:3])
    float inv1 = rsqrtf(a[0]*a[0] + a[1]*a[1] + a[2]*a[2]);
    float b10 = a[0]*inv1, b11 = a[1]*inv1, b12 = a[2]*inv1;
    // b2 = normalize(a[3:6] - (b1.a2) b1)
    float d = b10*a[3] + b11*a[4] + b12*a[5];
    float c0 = a[3] - d*b10, c1 = a[4] - d*b11, c2 = a[5] - d*b12;
    float inv2 = rsqrtf(c0*c0 + c1*c1 + c2*c2);
    float b20 = c0*inv2, b21 = c1*inv2, b22 = c2*inv2;
    R[0] = b10; R[1] = b11; R[2] = b12;
    R[3] = b20; R[4] = b21; R[5] = b22;
    // b3 = b1 x b2
    R[6] = b11*b22 - b12*b21;
    R[7] = b12*b20 - b10*b22;
    R[8] = b10*b21 - b11*b20;
}

__global__ __launch_bounds__(256) void skel_kernel(
    const float* __restrict__ angles,
    const float* __restrict__ xyz,
    float* __restrict__ out,
    int batch)
{
    const int b = blockIdx.x * 256 + threadIdx.x;
    if (b >= batch) return;

    const float2* ab2 = (const float2*)(angles + (size_t)b * (NJ * 6));

    float o[NJ * 3];
    float a[6], R[9], Rw[9], pw[3], Rw3[9], pw3[3];

    // ---- joint 0: Rw = R0, pw = R0 @ ref[0] ----
    {
        float2 v0 = ab2[0], v1 = ab2[1], v2 = ab2[2];
        a[0] = v0.x; a[1] = v0.y; a[2] = v1.x;
        a[3] = v1.y; a[4] = v2.x; a[5] = v2.y;
    }
    rot6d(a, Rw);
    {
        float x = xyz[0], y = xyz[1], z = xyz[2];
        pw[0] = Rw[0]*x + Rw[1]*y + Rw[2]*z;
        pw[1] = Rw[3]*x + Rw[4]*y + Rw[5]*z;
        pw[2] = Rw[6]*x + Rw[7]*y + Rw[8]*z;
    }
    o[0] = pw[0]; o[1] = pw[1]; o[2] = pw[2];

    // tree edges (parent -> child = e+1); chains 0-1-2-3, 3-4-5, 3-6..10, 3-11..15
    constexpr int PAR[15] = {0, 1, 2, 3, 4, 3, 6, 7, 8, 9, 3, 11, 12, 13, 14};

#pragma unroll
    for (int e = 0; e < 15; ++e) {
        const int c = e + 1;
        const int p = PAR[e];

        if (p == 3) {  // branch restart: restore saved state at joint 3
#pragma unroll
            for (int k = 0; k < 9; ++k) Rw[k] = Rw3[k];
            pw[0] = pw3[0]; pw[1] = pw3[1]; pw[2] = pw3[2];
        }

        // local rotation for child c
        {
            float2 v0 = ab2[c * 3 + 0], v1 = ab2[c * 3 + 1], v2 = ab2[c * 3 + 2];
            a[0] = v0.x; a[1] = v0.y; a[2] = v1.x;
            a[3] = v1.y; a[4] = v2.x; a[5] = v2.y;
        }
        rot6d(a, R);

        // t = ref[c] - ref[p]  (wave-uniform scalar loads)
        float tx = xyz[c * 3 + 0] - xyz[p * 3 + 0];
        float ty = xyz[c * 3 + 1] - xyz[p * 3 + 1];
        float tz = xyz[c * 3 + 2] - xyz[p * 3 + 2];

        // local_t = R @ t
        float lt0 = R[0]*tx + R[1]*ty + R[2]*tz;
        float lt1 = R[3]*tx + R[4]*ty + R[5]*tz;
        float lt2 = R[6]*tx + R[7]*ty + R[8]*tz;

        // pw[c] = Rw[p] @ local_t + pw[p]
        float np0 = Rw[0]*lt0 + Rw[1]*lt1 + Rw[2]*lt2 + pw[0];
        float np1 = Rw[3]*lt0 + Rw[4]*lt1 + Rw[5]*lt2 + pw[1];
        float np2 = Rw[6]*lt0 + Rw[7]*lt1 + Rw[8]*lt2 + pw[2];

        // Rw[c] = Rw[p] @ R[c]
        float T[9];
#pragma unroll
        for (int i = 0; i < 3; ++i)
#pragma unroll
            for (int j = 0; j < 3; ++j)
                T[i*3 + j] = Rw[i*3 + 0]*R[0*3 + j]
                           + Rw[i*3 + 1]*R[1*3 + j]
                           + Rw[i*3 + 2]*R[2*3 + j];
#pragma unroll
        for (int k = 0; k < 9; ++k) Rw[k] = T[k];
        pw[0] = np0; pw[1] = np1; pw[2] = np2;

        o[c*3 + 0] = np0; o[c*3 + 1] = np1; o[c*3 + 2] = np2;

        if (c == 3) {  // save branch point (children 4, 6, 11)
#pragma unroll
            for (int k = 0; k < 9; ++k) Rw3[k] = Rw[k];
            pw3[0] = pw[0]; pw3[1] = pw[1]; pw3[2] = pw[2];
        }
    }

    // coalesced-per-lane vectorized store: 12 x float4 = 48 floats
    float4* o4 = (float4*)(out + (size_t)b * (NJ * 3));
#pragma unroll
    for (int k = 0; k < 12; ++k)
        o4[k] = make_float4(o[4*k + 0], o[4*k + 1], o[4*k + 2], o[4*k + 3]);
}

} // namespace

extern "C" void kernel_launch(void* const* d_in, const int* in_sizes, int n_in,
                              void* d_out, int out_size, void* d_ws, size_t ws_size,
                              hipStream_t stream) {
    const float* angles = (const float*)d_in[0];   // [B, 16, 6] f32
    const float* xyz    = (const float*)d_in[1];   // [1, 16, 3] f32
    float* out          = (float*)d_out;           // [B, 16, 3] f32

    const int batch = in_sizes[0] / (NJ * 6);
    dim3 grid((batch + 255) / 256);
    skel_kernel<<<grid, 256, 0, stream>>>(angles, xyz, out, batch);
}